// Round 8
// baseline (163.254 us; speedup 1.0000x reference)
//
#include <hip/hip_runtime.h>

// NTXentLoss, B=8192, D=128, T=0.1, idx=0. fp32 in, fp32 scalar out.
// R7 post-mortem: L2-direct fragment streaming regressed (71 us) -- L2
// latency on every fragment load, no reuse. R8: back to LDS, but stage the
// ENTIRE K=128 tile pair up-front (64 KB static LDS exactly, m132 precedent),
// ONE barrier per block, then 64 MFMAs/wave barrier-free. Layout = R5's
// measured-zero-conflict pattern (64-K halves, 128-B rows, slot = kq^(m&7)).
// Labels via direct L2 loads; rowsum via shuffle + global atomics.

#define BB 8192
#define DD 128
#define TM 128
#define TN 128

typedef __attribute__((ext_vector_type(8))) short short8;
typedef __attribute__((ext_vector_type(4))) float floatx4;

#define GLOBAL_AS __attribute__((address_space(1)))
#define LDS_AS    __attribute__((address_space(3)))

static __device__ __forceinline__ float wave_sum(float v) {
#pragma unroll
    for (int off = 32; off > 0; off >>= 1) v += __shfl_xor(v, off, 64);
    return v;
}

static __device__ __forceinline__ unsigned short f2bf(float f) {
    unsigned int u = __float_as_uint(f);
    return (unsigned short)((u + 0x7FFFu + ((u >> 16) & 1u)) >> 16);
}

// ---- prep: normalize rows -> bf16 copies + 1/norm; zero denom and out ----
__global__ __launch_bounds__(256) void prep_kernel(
    const float* __restrict__ zis, const float* __restrict__ zjs,
    unsigned short* __restrict__ Zib, unsigned short* __restrict__ Zjb,
    float* __restrict__ rni, float* __restrict__ rnj,
    float* __restrict__ denom, float* __restrict__ out)
{
    int tid = threadIdx.x;
    if (blockIdx.x < 32) denom[blockIdx.x * 256 + tid] = 0.0f;   // 32*256 = BB
    if (blockIdx.x == 0 && tid == 0) out[0] = 0.0f;

    int wave = tid >> 6, lane = tid & 63;
    int row = blockIdx.x * 4 + wave;
    const float* src; unsigned short* dst; float* rn; int r;
    if (row < BB) { src = zis; dst = Zib; rn = rni; r = row; }
    else          { src = zjs; dst = Zjb; rn = rnj; r = row - BB; }
    float2 u = *(const float2*)(src + (size_t)r * DD + lane * 2);
    float s = wave_sum(u.x * u.x + u.y * u.y);
    float sc = 1.0f / sqrtf(s);
    if (lane == 0) rn[r] = sc;
    ushort2 o; o.x = f2bf(u.x * sc); o.y = f2bf(u.y * sc);
    *(ushort2*)(dst + (size_t)r * DD + lane * 2) = o;
}

// ---- 128x128 MFMA tile: full-K up-front staging, single barrier ----------
// LDS exactly 64 KB: A/B x 2 k-halves, each [128 rows][64 k] bf16 (16 KB).
// Region = 8 rows x 64 k = 1 KB; lane l -> row (l>>3), k-quad (l&7)^(l>>3),
// LDS dst = base + l*16 (HW lane scatter) => stored slot = kq ^ (row&7).
// Read: frag(m,kq) at m*64 + ((kq^(m&7))<<3) shorts -- R5-measured 0 conflicts.
__global__ __launch_bounds__(256) void mfma_tile_kernel(
    const unsigned short* __restrict__ Zjb,   // A: zj normalized
    const unsigned short* __restrict__ Zib,   // B: zi normalized
    const int* __restrict__ ilab, const int* __restrict__ jlab,
    float* __restrict__ denom)
{
    __shared__ __align__(16) unsigned short At[2][TM * 64];  // 2 x 16 KB
    __shared__ __align__(16) unsigned short Bt[2][TN * 64];  // 2 x 16 KB

    int tid  = threadIdx.x;
    int lane = tid & 63, wave = tid >> 6;
    int wm = wave >> 1, wn = wave & 1;        // 2x2 wave grid, 64x64 each
    int quad = lane >> 4, l15 = lane & 15;
    int i0 = blockIdx.y * TM, j0 = blockIdx.x * TN;

    const unsigned short* srcA = Zjb + (size_t)i0 * DD;
    const unsigned short* srcB = Zib + (size_t)j0 * DD;

    // ---- stage all 64 regions (16 per wave), then ONE barrier ----
    int srow8 = lane >> 3;              // 0..7
    int kq_l  = (lane & 7) ^ srow8;     // swizzle in the global address
#pragma unroll
    for (int t = 0; t < 16; ++t) {
        int g = wave + t * 4;           // 0..63
        int half = g >> 5;              // k-half
        int isA  = (g >> 4) & 1;        // within half: 0 -> A, 1 -> B
        int rg   = g & 15;              // region: 8 rows
        int rowl = rg * 8 + srow8;
        const unsigned short* gp = (isA ? srcA : srcB)
            + (size_t)rowl * DD + half * 64 + kq_l * 8;
        unsigned short* lp = (isA ? &At[half][rg * 512] : &Bt[half][rg * 512]);
        __builtin_amdgcn_global_load_lds((const GLOBAL_AS void*)gp,
                                         (LDS_AS void*)lp, 16, 0, 0);
    }
    __syncthreads();                    // the only barrier

    floatx4 acc[4][4];
#pragma unroll
    for (int a = 0; a < 4; ++a)
#pragma unroll
        for (int b = 0; b < 4; ++b) acc[a][b] = (floatx4){0.f, 0.f, 0.f, 0.f};

#pragma unroll
    for (int kh = 0; kh < 2; ++kh) {
#pragma unroll
        for (int kc = 0; kc < 2; ++kc) {
            int kq = kc * 4 + quad;
            short8 af[4], bfr[4];
#pragma unroll
            for (int t = 0; t < 4; ++t) {
                int m = wm * 64 + t * 16 + l15;
                af[t]  = *(const short8*)&At[kh][m * 64 + ((kq ^ (m & 7)) << 3)];
                int n = wn * 64 + t * 16 + l15;
                bfr[t] = *(const short8*)&Bt[kh][n * 64 + ((kq ^ (n & 7)) << 3)];
            }
#pragma unroll
            for (int mt = 0; mt < 4; ++mt)
#pragma unroll
                for (int nt = 0; nt < 4; ++nt)
                    acc[mt][nt] = __builtin_amdgcn_mfma_f32_16x16x32_bf16(
                        af[mt], bfr[nt], acc[mt][nt], 0, 0, 0);
        }
    }

    // ---- epilogue: exp/mask/row-reduce; labels from L2; no LDS ----
    int ilv[4];
#pragma unroll
    for (int nt = 0; nt < 4; ++nt)
        ilv[nt] = ilab[j0 + wn * 64 + nt * 16 + l15];

#pragma unroll
    for (int mt = 0; mt < 4; ++mt) {
        float s4[4];
#pragma unroll
        for (int r = 0; r < 4; ++r) {
            int rowl = wm * 64 + mt * 16 + quad * 4 + r;
            int jr = jlab[i0 + rowl];
            float s = 0.0f;
#pragma unroll
            for (int nt = 0; nt < 4; ++nt) {
                float e = __expf(fmaf(acc[mt][nt][r], 10.0f, -10.0f));
                s += (ilv[nt] != jr) ? e : 0.0f;
            }
            s4[r] = s;
        }
        // reduce the 4 rows in parallel across l15 (bits 1,2,4,8)
#pragma unroll
        for (int step = 1; step <= 8; step <<= 1) {
#pragma unroll
            for (int r = 0; r < 4; ++r)
                s4[r] += __shfl_xor(s4[r], step, 64);
        }
        if (l15 == 0) {
#pragma unroll
            for (int r = 0; r < 4; ++r)
                atomicAdd(&denom[i0 + wm * 64 + mt * 16 + quad * 4 + r], s4[r]);
        }
    }
}

// ---- fused pos + finalize (512 blocks, 1 atomic/block) -------------------
__global__ __launch_bounds__(256) void posfinal_kernel(
    const float* __restrict__ zis, const float* __restrict__ zjs,
    const float* __restrict__ rni, const float* __restrict__ rnj,
    const float* __restrict__ denom, const float* __restrict__ wts,
    const int* __restrict__ idxp, float* __restrict__ out)
{
    int wave = threadIdx.x >> 6, lane = threadIdx.x & 63;
    int idx = idxp[0];
    float ll = 0.0f;
#pragma unroll
    for (int t = 0; t < 4; ++t) {
        int i = blockIdx.x * 16 + wave * 4 + t;
        int j = idx + i;
        float2 a  = *(const float2*)(zjs + (size_t)i * DD + lane * 2);
        float2 b2 = *(const float2*)(zis + (size_t)j * DD + lane * 2);
        float s = wave_sum(a.x * b2.x + a.y * b2.y);
        if (lane == 0) {
            float p = s * rni[j] * rnj[i] * 10.0f;
            float l = 10.0f + logf(__expf(p - 10.0f) + denom[i]) - p;
            float w = wts[j];
            ll += (l * w) / w;    // faithful to reference's weighted mean
        }
    }
    __shared__ float part[4];
    if (lane == 0) part[wave] = ll;
    __syncthreads();
    if (threadIdx.x == 0)
        atomicAdd(out, (part[0] + part[1] + part[2] + part[3]) * (1.0f / BB));
}

// ---- launch --------------------------------------------------------------
extern "C" void kernel_launch(void* const* d_in, const int* in_sizes, int n_in,
                              void* d_out, int out_size, void* d_ws, size_t ws_size,
                              hipStream_t stream) {
    const float* zis = (const float*)d_in[0];
    const float* zjs = (const float*)d_in[1];
    const int* ilab = (const int*)d_in[2];
    const int* jlab = (const int*)d_in[3];
    const float* wts = (const float*)d_in[4];
    const int* idxp = (const int*)d_in[5];
    float* out = (float*)d_out;

    float* rni   = (float*)d_ws;
    float* rnj   = rni + BB;
    float* denom = rnj + BB;
    unsigned short* Zib = (unsigned short*)(denom + BB);  // [BB][DD] bf16
    unsigned short* Zjb = Zib + (size_t)BB * DD;

    prep_kernel<<<2 * BB / 4, 256, 0, stream>>>(
        zis, zjs, Zib, Zjb, rni, rnj, denom, out);
    mfma_tile_kernel<<<dim3(BB / TN, BB / TM), 256, 0, stream>>>(
        Zjb, Zib, ilab, jlab, denom);
    posfinal_kernel<<<BB / 16, 256, 0, stream>>>(
        zis, zjs, rni, rnj, denom, wts, idxp, out);
}